// Round 5
// baseline (130.402 us; speedup 1.0000x reference)
//
#include <hip/hip_runtime.h>
#include <hip/hip_fp16.h>

#define NQ 12
#define DEPTH 8
#define NCLASS 10
#define BATCH 4096
#define LSTRIDE_H 72   // LDS row stride in HALVES (144 B, mult of 16 for b128)
#define WPB 2          // waves (= samples) per block; LDS = 2*64*72*2 = 18432 B -> 8 blocks/CU

// ---------------------------------------------------------------------------
// One wave per sample; statevector (4096 amps) lives in v[64] fp32 per lane.
// Frame A: qubit q in 0..5  <-> lane bit (5-q);  q in 6..11 <-> reg bit (11-q)
// Frame B: qubit q in 0..5  <-> reg  bit (5-q);  q in 6..11 <-> lane bit (11-q)
// Per layer:
//   RT1: LDS round-trip implementing (transpose ∘ CNOT_odd ∘ CNOT_even), A->B
//   RY qubits 0..5   (reg-local in frame B, packed-f32 VALU)
//   RT2: plain transpose B->A
//   RY qubits 6..11  (reg-local in frame A, packed-f32 VALU)
// LDS staging in fp16 RTNE. All DS intra-wave (private region, DS in-order).
// __launch_bounds__(128, 1): R3/R4 showed this toolchain caps VGPR at
// 512/(arg2 * waves_per_block); arg2=1 -> cap 256 -> statevector stays in
// arch VGPRs (no AGPR shuttle around VOP3P), HW occupancy still 4 waves/SIMD.
// ---------------------------------------------------------------------------

typedef __attribute__((ext_vector_type(8))) unsigned short ushort8;  // 16 B
typedef __attribute__((ext_vector_type(2))) float float2v;

__device__ constexpr int hfun(int r) {  // src lane for RT1 output reg r (CNOT index map)
    const int rb5 = (r >> 5) & 1, rb4 = (r >> 4) & 1, rb3 = (r >> 3) & 1;
    const int rb2 = (r >> 2) & 1, rb1 = (r >> 1) & 1, rb0 = r & 1;
    const int c0 = rb5;
    const int c1 = rb4 ^ rb5;
    const int c2 = rb3 ^ rb4;
    const int c3 = rb2 ^ rb3 ^ rb4;
    const int c4 = rb1 ^ rb2;
    const int c5 = rb0 ^ rb1 ^ rb2;
    return (c0 << 5) | (c1 << 4) | (c2 << 3) | (c3 << 2) | (c4 << 1) | c5;
}

// RY pair rotation over reg bit mask M, written as float2 math so LLVM can
// emit v_pk_mul_f32 / v_pk_fma_f32 (2 instrs per 2 outputs).
template <int M>
__device__ __forceinline__ void ry_local(float (&v)[64], float cw, float sw) {
    if (M >= 2) {
#pragma unroll
        for (int r = 0; r < 64; r += 2) {
            if (r & M) continue;
            const int r1 = r | M;
            float2v A = {v[r], v[r + 1]};
            float2v B = {v[r1], v[r1 + 1]};
            float2v lo = cw * A - sw * B;
            float2v hi = sw * A + cw * B;
            v[r] = lo.x;  v[r + 1] = lo.y;
            v[r1] = hi.x; v[r1 + 1] = hi.y;
        }
    } else {
        const float2v C1 = {cw, sw}, C2 = {-sw, cw};
#pragma unroll
        for (int r = 0; r < 64; r += 2) {
            float2v res = C1 * v[r] + C2 * v[r + 1];
            v[r] = res.x; v[r + 1] = res.y;
        }
    }
}

__global__ __launch_bounds__(WPB * 64, 1) void vqc_kernel(const float* __restrict__ X,
                                                          const float* __restrict__ W,
                                                          float* __restrict__ out) {
    __shared__ __align__(16) unsigned short lds[WPB * 64 * LSTRIDE_H];

    const int lane   = threadIdx.x & 63;
    const int wid    = threadIdx.x >> 6;
    const int sample = blockIdx.x * WPB + wid;
    const int l      = lane;

    unsigned short* Wb   = &lds[wid * 64 * LSTRIDE_H];
    unsigned short* wrow = &Wb[l * LSTRIDE_H];        // row-major write base (16B aligned)
    const int G = l ^ (l >> 1) ^ ((l >> 2) & 5);      // src col l-part for RT1 (lane-local CNOTs)
    const unsigned short* rG0 = &Wb[G];               // r even (q5=0)
    const unsigned short* rG1 = &Wb[G ^ 0x30];        // r odd  (q5=1): CNOT(5,6) column flip
    const unsigned short* rT2 = &Wb[l];               // RT2 read base

    // ---- data encoding: product state, frame A ----
    float cx[NQ], sx[NQ];
#pragma unroll
    for (int q = 0; q < NQ; ++q) {
        float ang = 0.5f * X[sample * NQ + q] + 0.78539816339744831f;
        __sincosf(ang, &sx[q], &cx[q]);
    }
    float P = 1.0f;
#pragma unroll
    for (int q = 0; q < 6; ++q) P *= ((l >> (5 - q)) & 1) ? sx[q] : cx[q];

    float v[64];
    v[0] = P * cx[11];
    v[1] = P * sx[11];
#pragma unroll
    for (int lvl = 1; lvl < 6; ++lvl) {
        const int q = 11 - lvl;
#pragma unroll
        for (int j = 0; j < (1 << 5); ++j) {
            if (j >= (1 << lvl)) continue;
            v[j + (1 << lvl)] = v[j] * sx[q];
            v[j]              = v[j] * cx[q];
        }
    }

    // ---- variational layers ----
#pragma unroll 1
    for (int k = 0; k < DEPTH; ++k) {
        float cw[NQ], sw[NQ];
#pragma unroll
        for (int q = 0; q < NQ; ++q)
            __sincosf(0.5f * W[k * NQ + q], &sw[q], &cw[q]);

        // ---- RT1: frame A -> frame B with both CNOT groups folded (fp16 staging) ----
#pragma unroll
        for (int t = 0; t < 8; ++t) {
            ushort8 w;
#pragma unroll
            for (int i = 0; i < 8; ++i)
                w[i] = __half_as_ushort(__float2half(v[8 * t + i]));   // RTNE
            *(ushort8*)&wrow[8 * t] = w;
        }
#pragma unroll
        for (int r = 0; r < 64; ++r)
            v[r] = __half2float(__ushort_as_half(((r & 1) ? rG1 : rG0)[hfun(r) * LSTRIDE_H]));

        // ---- RY qubits 0..5 (frame B: qubit p <-> reg bit 5-p) ----
        ry_local<32>(v, cw[0], sw[0]);
        ry_local<16>(v, cw[1], sw[1]);
        ry_local<8>(v, cw[2], sw[2]);
        ry_local<4>(v, cw[3], sw[3]);
        ry_local<2>(v, cw[4], sw[4]);
        ry_local<1>(v, cw[5], sw[5]);

        // ---- RT2: plain transpose, frame B -> frame A (fp16 staging) ----
#pragma unroll
        for (int t = 0; t < 8; ++t) {
            ushort8 w;
#pragma unroll
            for (int i = 0; i < 8; ++i)
                w[i] = __half_as_ushort(__float2half(v[8 * t + i]));   // RTNE
            *(ushort8*)&wrow[8 * t] = w;
        }
#pragma unroll
        for (int j = 0; j < 64; ++j)
            v[j] = __half2float(__ushort_as_half(rT2[j * LSTRIDE_H]));

        // ---- RY qubits 6..11 (frame A: qubit p <-> reg bit 11-p) ----
        ry_local<32>(v, cw[6], sw[6]);
        ry_local<16>(v, cw[7], sw[7]);
        ry_local<8>(v, cw[8], sw[8]);
        ry_local<4>(v, cw[9], sw[9]);
        ry_local<2>(v, cw[10], sw[10]);
        ry_local<1>(v, cw[11], sw[11]);
    }

    // ---- measurement: <Z_p> = P(bit p = 0) - P(bit p = 1), frame A ----
#pragma unroll
    for (int j = 0; j < 64; ++j) v[j] *= v[j];

    float c2[16];  // summed over reg bits 0,1
#pragma unroll
    for (int m = 0; m < 16; ++m)
        c2[m] = (v[4 * m] + v[4 * m + 1]) + (v[4 * m + 2] + v[4 * m + 3]);

    float S = 0.0f;
#pragma unroll
    for (int m = 0; m < 16; ++m) S += c2[m];

    float T[4];  // signed sum on reg bit t+2
#pragma unroll
    for (int t = 0; t < 4; ++t) {
        float acc = 0.0f;
#pragma unroll
        for (int m = 0; m < 16; ++m) acc += ((m >> t) & 1) ? -c2[m] : c2[m];
        T[t] = acc;
    }

    float o[NCLASS];
#pragma unroll
    for (int p = 0; p < 6; ++p) {   // qubit p on lane bit (5-p)
        float r = ((l >> (5 - p)) & 1) ? -S : S;
#pragma unroll
        for (int m = 0; m < 6; ++m) r += __shfl_xor(r, 1 << m, 64);
        o[p] = r;
    }
#pragma unroll
    for (int p = 6; p < 10; ++p) {  // qubit p on reg bit (11-p) -> T[9-p]
        float r = T[9 - p];
#pragma unroll
        for (int m = 0; m < 6; ++m) r += __shfl_xor(r, 1 << m, 64);
        o[p] = r;
    }

    if (lane == 0) {
#pragma unroll
        for (int p = 0; p < NCLASS; ++p) out[sample * NCLASS + p] = o[p];
    }
}

extern "C" void kernel_launch(void* const* d_in, const int* in_sizes, int n_in,
                              void* d_out, int out_size, void* d_ws, size_t ws_size,
                              hipStream_t stream) {
    const float* X = (const float*)d_in[0];
    const float* W = (const float*)d_in[1];
    float* out     = (float*)d_out;
    (void)in_sizes; (void)n_in; (void)out_size; (void)d_ws; (void)ws_size;

    dim3 grid(BATCH / WPB);
    dim3 block(WPB * 64);
    hipLaunchKernelGGL(vqc_kernel, grid, block, 0, stream, X, W, out);
}

// Round 7
// 114.000 us; speedup vs baseline: 1.1439x; 1.1439x over previous
//
#include <hip/hip_runtime.h>
#include <hip/hip_fp16.h>

#define NQ 12
#define DEPTH 8
#define NCLASS 10
#define BATCH 4096
#define LSTRIDE 68   // LDS row stride in DWORDS (272 B; 16B-aligned rows; bank phase 4l -> <=2-way)
#define WPB 2        // waves per block; 2 samples/wave; LDS = 2*64*68*4 = 34816 B

// ---------------------------------------------------------------------------
// One wave per TWO samples. Statevector amplitude (12-bit index) for both
// samples packed as __half2 (lo=sample0, hi=sample1) in v[64] per lane.
// Frame A: qubit q in 0..5  <-> lane bit (5-q);  q in 6..11 <-> reg bit (11-q)
// Frame B: qubit q in 0..5  <-> reg  bit (5-q);  q in 6..11 <-> lane bit (11-q)
// Per layer:
//   RT1: LDS round-trip = (transpose ∘ CNOT_odd ∘ CNOT_even), A->B.
//        Element = dword (half2 pair); direct reads col[hfun(r)*LSTRIDE]
//        (compile-time immediate offsets; R6's read-pairing had hfun(r^2)
//        = hfun(r)^3 not ^2 -> permutation bug, and ds_read2 can't merge
//        offsets > 1020 B anyway).
//   RY qubits 0..5   (reg-local in frame B, v_pk_fma_f16; weights shared
//                     across the two samples so one pk op rotates both)
//   RT2: plain transpose B->A, direct reads rT2[j*LSTRIDE].
//   RY qubits 6..11  (reg-local in frame A, pk f16)
// All DS intra-wave (private region per wave, DS in-order) -> no barriers.
// ---------------------------------------------------------------------------

__device__ __forceinline__ uint32_t h2u(__half2 x) { return __builtin_bit_cast(uint32_t, x); }
__device__ __forceinline__ __half2 u2h(uint32_t x) { return __builtin_bit_cast(__half2, x); }

__device__ constexpr int hfun(int r) {  // src row (old lane) for RT1 output reg r
    const int rb5 = (r >> 5) & 1, rb4 = (r >> 4) & 1, rb3 = (r >> 3) & 1;
    const int rb2 = (r >> 2) & 1, rb1 = (r >> 1) & 1, rb0 = r & 1;
    const int c0 = rb5;
    const int c1 = rb4 ^ rb5;
    const int c2 = rb3 ^ rb4;
    const int c3 = rb2 ^ rb3 ^ rb4;
    const int c4 = rb1 ^ rb2;
    const int c5 = rb0 ^ rb1 ^ rb2;
    return (c0 << 5) | (c1 << 4) | (c2 << 3) | (c3 << 2) | (c4 << 1) | c5;
}

// RY pair rotation over reg-bit mask M in packed fp16 (both samples at once).
template <int M>
__device__ __forceinline__ void ry16(__half2 (&v)[64], __half2 C2, __half2 S2, __half2 Sn2) {
#pragma unroll
    for (int r = 0; r < 64; ++r) {
        if (r & M) continue;
        const int r1 = r | M;
        const __half2 a = v[r], b = v[r1];
        v[r]  = __hfma2(C2, a, __hmul2(Sn2, b));   // cw*a - sw*b
        v[r1] = __hfma2(C2, b, __hmul2(S2, a));    // sw*a + cw*b
    }
}

__global__ __launch_bounds__(WPB * 64) void vqc_kernel(const float* __restrict__ X,
                                                       const float* __restrict__ W,
                                                       float* __restrict__ out) {
    __shared__ __align__(16) uint32_t lds[WPB * 64 * LSTRIDE];

    const int lane = threadIdx.x & 63;
    const int wid  = threadIdx.x >> 6;
    const int gw   = blockIdx.x * WPB + wid;   // global wave id
    const int s0   = 2 * gw, s1 = s0 + 1;      // the two samples
    const int l    = lane;

    uint32_t* Wb   = &lds[wid * 64 * LSTRIDE];
    uint32_t* wrow = &Wb[l * LSTRIDE];                 // staging write base (16B aligned)
    const int G = l ^ (l >> 1) ^ ((l >> 2) & 5);       // RT1 src col (lane-local CNOTs folded)
    const uint32_t* colA = &Wb[G];                     // r even (q5=0)
    const uint32_t* colB = &Wb[G ^ 0x30];              // r odd  (q5=1): CNOT(5,6) col flip
    const uint32_t* rT2  = &Wb[l];                     // RT2 read base

    // ---- data encoding: product state for both samples, frame A ----
    float cx0[NQ], sx0[NQ], cx1[NQ], sx1[NQ];
#pragma unroll
    for (int q = 0; q < NQ; ++q) {
        __sincosf(0.5f * X[s0 * NQ + q] + 0.78539816339744831f, &sx0[q], &cx0[q]);
        __sincosf(0.5f * X[s1 * NQ + q] + 0.78539816339744831f, &sx1[q], &cx1[q]);
    }
    float P0 = 1.0f, P1 = 1.0f;
#pragma unroll
    for (int q = 0; q < 6; ++q) {
        P0 *= ((l >> (5 - q)) & 1) ? sx0[q] : cx0[q];
        P1 *= ((l >> (5 - q)) & 1) ? sx1[q] : cx1[q];
    }

    __half2 v[64];
    v[0] = __floats2half2_rn(P0 * cx0[11], P1 * cx1[11]);
    v[1] = __floats2half2_rn(P0 * sx0[11], P1 * sx1[11]);
#pragma unroll
    for (int lvl = 1; lvl < 6; ++lvl) {
        const int q = 11 - lvl;
        const __half2 SX = __floats2half2_rn(sx0[q], sx1[q]);
        const __half2 CX = __floats2half2_rn(cx0[q], cx1[q]);
#pragma unroll
        for (int j = 0; j < (1 << 5); ++j) {
            if (j >= (1 << lvl)) continue;
            v[j + (1 << lvl)] = __hmul2(v[j], SX);
            v[j]              = __hmul2(v[j], CX);
        }
    }

    // ---- variational layers ----
#pragma unroll 1
    for (int k = 0; k < DEPTH; ++k) {
        // ---- RT1: frame A -> frame B with both CNOT groups folded ----
#pragma unroll
        for (int t = 0; t < 16; ++t) {
            uint4 w = make_uint4(h2u(v[4 * t]), h2u(v[4 * t + 1]),
                                 h2u(v[4 * t + 2]), h2u(v[4 * t + 3]));
            *(uint4*)&wrow[4 * t] = w;
        }
#pragma unroll
        for (int r = 0; r < 64; ++r)
            v[r] = u2h(((r & 1) ? colB : colA)[hfun(r) * LSTRIDE]);

        // ---- RY qubits 0..5 (frame B: qubit p <-> reg bit 5-p), pk f16 ----
#pragma unroll
        for (int p = 0; p < 6; ++p) {
            float cw, sw;
            __sincosf(0.5f * W[k * NQ + p], &sw, &cw);
            const __half2 C2  = __floats2half2_rn(cw, cw);
            const __half2 S2  = __floats2half2_rn(sw, sw);
            const __half2 Sn2 = __floats2half2_rn(-sw, -sw);
            switch (p) {
                case 0: ry16<32>(v, C2, S2, Sn2); break;
                case 1: ry16<16>(v, C2, S2, Sn2); break;
                case 2: ry16<8>(v, C2, S2, Sn2); break;
                case 3: ry16<4>(v, C2, S2, Sn2); break;
                case 4: ry16<2>(v, C2, S2, Sn2); break;
                case 5: ry16<1>(v, C2, S2, Sn2); break;
            }
        }

        // ---- RT2: plain transpose, frame B -> frame A ----
#pragma unroll
        for (int t = 0; t < 16; ++t) {
            uint4 w = make_uint4(h2u(v[4 * t]), h2u(v[4 * t + 1]),
                                 h2u(v[4 * t + 2]), h2u(v[4 * t + 3]));
            *(uint4*)&wrow[4 * t] = w;
        }
#pragma unroll
        for (int j = 0; j < 64; ++j)
            v[j] = u2h(rT2[j * LSTRIDE]);

        // ---- RY qubits 6..11 (frame A: qubit p <-> reg bit 11-p), pk f16 ----
#pragma unroll
        for (int p = 6; p < NQ; ++p) {
            float cw, sw;
            __sincosf(0.5f * W[k * NQ + p], &sw, &cw);
            const __half2 C2  = __floats2half2_rn(cw, cw);
            const __half2 S2  = __floats2half2_rn(sw, sw);
            const __half2 Sn2 = __floats2half2_rn(-sw, -sw);
            switch (p) {
                case 6:  ry16<32>(v, C2, S2, Sn2); break;
                case 7:  ry16<16>(v, C2, S2, Sn2); break;
                case 8:  ry16<8>(v, C2, S2, Sn2); break;
                case 9:  ry16<4>(v, C2, S2, Sn2); break;
                case 10: ry16<2>(v, C2, S2, Sn2); break;
                case 11: ry16<1>(v, C2, S2, Sn2); break;
            }
        }
    }

    // ---- measurement (fp32): <Z_p> per sample, frame A ----
    float c20[16], c21[16];
#pragma unroll
    for (int m = 0; m < 16; ++m) {
        float a0 = 0.0f, a1 = 0.0f;
#pragma unroll
        for (int i = 0; i < 4; ++i) {
            const float2 f = __half22float2(v[4 * m + i]);
            a0 += f.x * f.x;
            a1 += f.y * f.y;
        }
        c20[m] = a0;
        c21[m] = a1;
    }

    float S0 = 0.0f, S1 = 0.0f;
#pragma unroll
    for (int m = 0; m < 16; ++m) { S0 += c20[m]; S1 += c21[m]; }

    float T0[4], T1[4];
#pragma unroll
    for (int t = 0; t < 4; ++t) {
        float a0 = 0.0f, a1 = 0.0f;
#pragma unroll
        for (int m = 0; m < 16; ++m) {
            const float sgn = ((m >> t) & 1) ? -1.0f : 1.0f;
            a0 += sgn * c20[m];
            a1 += sgn * c21[m];
        }
        T0[t] = a0;
        T1[t] = a1;
    }

    float o0[NCLASS], o1[NCLASS];
#pragma unroll
    for (int p = 0; p < 6; ++p) {   // qubit p on lane bit (5-p)
        const float sgn = ((l >> (5 - p)) & 1) ? -1.0f : 1.0f;
        float r0 = sgn * S0, r1 = sgn * S1;
#pragma unroll
        for (int m = 0; m < 6; ++m) { r0 += __shfl_xor(r0, 1 << m, 64); r1 += __shfl_xor(r1, 1 << m, 64); }
        o0[p] = r0; o1[p] = r1;
    }
#pragma unroll
    for (int p = 6; p < 10; ++p) {  // qubit p on reg bit (11-p) -> T[9-p]
        float r0 = T0[9 - p], r1 = T1[9 - p];
#pragma unroll
        for (int m = 0; m < 6; ++m) { r0 += __shfl_xor(r0, 1 << m, 64); r1 += __shfl_xor(r1, 1 << m, 64); }
        o0[p] = r0; o1[p] = r1;
    }

    if (lane == 0) {
#pragma unroll
        for (int p = 0; p < NCLASS; ++p) {
            out[s0 * NCLASS + p] = o0[p];
            out[s1 * NCLASS + p] = o1[p];
        }
    }
}

extern "C" void kernel_launch(void* const* d_in, const int* in_sizes, int n_in,
                              void* d_out, int out_size, void* d_ws, size_t ws_size,
                              hipStream_t stream) {
    const float* X = (const float*)d_in[0];
    const float* W = (const float*)d_in[1];
    float* out     = (float*)d_out;
    (void)in_sizes; (void)n_in; (void)out_size; (void)d_ws; (void)ws_size;

    dim3 grid(BATCH / (2 * WPB));   // 2 samples per wave, WPB waves per block
    dim3 block(WPB * 64);
    hipLaunchKernelGGL(vqc_kernel, grid, block, 0, stream, X, W, out);
}

// Round 8
// 96.650 us; speedup vs baseline: 1.3492x; 1.1795x over previous
//
#include <hip/hip_runtime.h>
#include <hip/hip_fp16.h>

#define NQ 12
#define DEPTH 8
#define NCLASS 10
#define BATCH 4096
#define LSTRIDE 68   // LDS row stride in DWORDS (272 B; 16B-aligned rows; bank phase 4l -> <=2-way)
#define WPB 2        // waves per block; 2 samples/wave; LDS = 2*64*68*4 = 34816 B

// ---------------------------------------------------------------------------
// One wave per TWO samples. Statevector amplitude (12-bit index) for both
// samples packed as __half2 (lo=sample0, hi=sample1) in v[64] per lane.
// Frame A: qubit q in 0..5  <-> lane bit (5-q);  q in 6..11 <-> reg bit (11-q)
// Frame B: qubit q in 0..5  <-> reg  bit (5-q);  q in 6..11 <-> lane bit (11-q)
// Per layer:
//   RT1: LDS round-trip = (transpose ∘ CNOT_odd ∘ CNOT_even), A->B.
//   SHEAR-RY qubits 0..5  (frame B, reg-local): RY = c*[[1,-t],[t,1]] with
//        t = tan(w/2); apply the shear only (1 v_pk_fma_f16 per output),
//        accumulate C = prod cos(w/2) in fp32, scale final sums by C^2.
//   RT2: plain transpose B->A.
//   SHEAR-RY qubits 6..11 (frame A, reg-local).
// All DS intra-wave (private region per wave, DS in-order) -> no barriers.
// ---------------------------------------------------------------------------

__device__ __forceinline__ uint32_t h2u(__half2 x) { return __builtin_bit_cast(uint32_t, x); }
__device__ __forceinline__ __half2 u2h(uint32_t x) { return __builtin_bit_cast(__half2, x); }

__device__ constexpr int hfun(int r) {  // src row (old lane) for RT1 output reg r
    const int rb5 = (r >> 5) & 1, rb4 = (r >> 4) & 1, rb3 = (r >> 3) & 1;
    const int rb2 = (r >> 2) & 1, rb1 = (r >> 1) & 1, rb0 = r & 1;
    const int c0 = rb5;
    const int c1 = rb4 ^ rb5;
    const int c2 = rb3 ^ rb4;
    const int c3 = rb2 ^ rb3 ^ rb4;
    const int c4 = rb1 ^ rb2;
    const int c5 = rb0 ^ rb1 ^ rb2;
    return (c0 << 5) | (c1 << 4) | (c2 << 3) | (c3 << 2) | (c4 << 1) | c5;
}

// Shear rotation over reg-bit mask M in packed fp16 (both samples at once):
// a' = a - t*b ; b' = b + t*a   (1 pk_fma per output)
template <int M>
__device__ __forceinline__ void shear16(__half2 (&v)[64], __half2 T2, __half2 Tn2) {
#pragma unroll
    for (int r = 0; r < 64; ++r) {
        if (r & M) continue;
        const int r1 = r | M;
        const __half2 a = v[r], b = v[r1];
        v[r]  = __hfma2(Tn2, b, a);
        v[r1] = __hfma2(T2, a, b);
    }
}

__global__ __launch_bounds__(WPB * 64) void vqc_kernel(const float* __restrict__ X,
                                                       const float* __restrict__ W,
                                                       float* __restrict__ out) {
    __shared__ __align__(16) uint32_t lds[WPB * 64 * LSTRIDE];

    const int lane = threadIdx.x & 63;
    const int wid  = threadIdx.x >> 6;
    const int gw   = blockIdx.x * WPB + wid;   // global wave id
    const int s0   = 2 * gw, s1 = s0 + 1;      // the two samples
    const int l    = lane;

    uint32_t* Wb   = &lds[wid * 64 * LSTRIDE];
    uint32_t* wrow = &Wb[l * LSTRIDE];                 // staging write base (16B aligned)
    const int G = l ^ (l >> 1) ^ ((l >> 2) & 5);       // RT1 src col (lane-local CNOTs folded)
    const uint32_t* colA = &Wb[G];                     // r even (q5=0)
    const uint32_t* colB = &Wb[G ^ 0x30];              // r odd  (q5=1): CNOT(5,6) col flip
    const uint32_t* rT2  = &Wb[l];                     // RT2 read base

    // ---- data encoding: product state for both samples, frame A ----
    float cx0[NQ], sx0[NQ], cx1[NQ], sx1[NQ];
#pragma unroll
    for (int q = 0; q < NQ; ++q) {
        __sincosf(0.5f * X[s0 * NQ + q] + 0.78539816339744831f, &sx0[q], &cx0[q]);
        __sincosf(0.5f * X[s1 * NQ + q] + 0.78539816339744831f, &sx1[q], &cx1[q]);
    }
    float P0 = 1.0f, P1 = 1.0f;
#pragma unroll
    for (int q = 0; q < 6; ++q) {
        P0 *= ((l >> (5 - q)) & 1) ? sx0[q] : cx0[q];
        P1 *= ((l >> (5 - q)) & 1) ? sx1[q] : cx1[q];
    }

    __half2 v[64];
    v[0] = __floats2half2_rn(P0 * cx0[11], P1 * cx1[11]);
    v[1] = __floats2half2_rn(P0 * sx0[11], P1 * sx1[11]);
#pragma unroll
    for (int lvl = 1; lvl < 6; ++lvl) {
        const int q = 11 - lvl;
        const __half2 SX = __floats2half2_rn(sx0[q], sx1[q]);
        const __half2 CX = __floats2half2_rn(cx0[q], cx1[q]);
#pragma unroll
        for (int j = 0; j < (1 << 5); ++j) {
            if (j >= (1 << lvl)) continue;
            v[j + (1 << lvl)] = __hmul2(v[j], SX);
            v[j]              = __hmul2(v[j], CX);
        }
    }

    float Call = 1.0f;   // product of cos(w/2) over all gates (deferred scale)

    // ---- variational layers ----
#pragma unroll 1
    for (int k = 0; k < DEPTH; ++k) {
        // ---- RT1: frame A -> frame B with both CNOT groups folded ----
#pragma unroll
        for (int t = 0; t < 16; ++t) {
            uint4 w = make_uint4(h2u(v[4 * t]), h2u(v[4 * t + 1]),
                                 h2u(v[4 * t + 2]), h2u(v[4 * t + 3]));
            *(uint4*)&wrow[4 * t] = w;
        }
#pragma unroll
        for (int r = 0; r < 64; ++r)
            v[r] = u2h(((r & 1) ? colB : colA)[hfun(r) * LSTRIDE]);

        // ---- shear-RY qubits 0..5 (frame B: qubit p <-> reg bit 5-p) ----
#pragma unroll
        for (int p = 0; p < 6; ++p) {
            float cw, sw;
            __sincosf(0.5f * W[k * NQ + p], &sw, &cw);
            Call *= cw;
            const float t = sw / cw;
            const __half2 T2  = __floats2half2_rn(t, t);
            const __half2 Tn2 = __floats2half2_rn(-t, -t);
            switch (p) {
                case 0: shear16<32>(v, T2, Tn2); break;
                case 1: shear16<16>(v, T2, Tn2); break;
                case 2: shear16<8>(v, T2, Tn2); break;
                case 3: shear16<4>(v, T2, Tn2); break;
                case 4: shear16<2>(v, T2, Tn2); break;
                case 5: shear16<1>(v, T2, Tn2); break;
            }
        }

        // ---- RT2: plain transpose, frame B -> frame A ----
#pragma unroll
        for (int t = 0; t < 16; ++t) {
            uint4 w = make_uint4(h2u(v[4 * t]), h2u(v[4 * t + 1]),
                                 h2u(v[4 * t + 2]), h2u(v[4 * t + 3]));
            *(uint4*)&wrow[4 * t] = w;
        }
#pragma unroll
        for (int j = 0; j < 64; ++j)
            v[j] = u2h(rT2[j * LSTRIDE]);

        // ---- shear-RY qubits 6..11 (frame A: qubit p <-> reg bit 11-p) ----
#pragma unroll
        for (int p = 6; p < NQ; ++p) {
            float cw, sw;
            __sincosf(0.5f * W[k * NQ + p], &sw, &cw);
            Call *= cw;
            const float t = sw / cw;
            const __half2 T2  = __floats2half2_rn(t, t);
            const __half2 Tn2 = __floats2half2_rn(-t, -t);
            switch (p) {
                case 6:  shear16<32>(v, T2, Tn2); break;
                case 7:  shear16<16>(v, T2, Tn2); break;
                case 8:  shear16<8>(v, T2, Tn2); break;
                case 9:  shear16<4>(v, T2, Tn2); break;
                case 10: shear16<2>(v, T2, Tn2); break;
                case 11: shear16<1>(v, T2, Tn2); break;
            }
        }
    }

    const float C2 = (Call * Call);   // deferred |amplitude|^2 scale

    // ---- measurement (fp32): <Z_p> per sample, frame A ----
    float c20[16], c21[16];
#pragma unroll
    for (int m = 0; m < 16; ++m) {
        float a0 = 0.0f, a1 = 0.0f;
#pragma unroll
        for (int i = 0; i < 4; ++i) {
            const float2 f = __half22float2(v[4 * m + i]);
            a0 += f.x * f.x;
            a1 += f.y * f.y;
        }
        c20[m] = a0;
        c21[m] = a1;
    }

    float S0 = 0.0f, S1 = 0.0f;
#pragma unroll
    for (int m = 0; m < 16; ++m) { S0 += c20[m]; S1 += c21[m]; }
    S0 *= C2; S1 *= C2;

    float T0[4], T1[4];
#pragma unroll
    for (int t = 0; t < 4; ++t) {
        float a0 = 0.0f, a1 = 0.0f;
#pragma unroll
        for (int m = 0; m < 16; ++m) {
            const float sgn = ((m >> t) & 1) ? -1.0f : 1.0f;
            a0 += sgn * c20[m];
            a1 += sgn * c21[m];
        }
        T0[t] = a0 * C2;
        T1[t] = a1 * C2;
    }

    float o0[NCLASS], o1[NCLASS];
#pragma unroll
    for (int p = 0; p < 6; ++p) {   // qubit p on lane bit (5-p)
        const float sgn = ((l >> (5 - p)) & 1) ? -1.0f : 1.0f;
        float r0 = sgn * S0, r1 = sgn * S1;
#pragma unroll
        for (int m = 0; m < 6; ++m) { r0 += __shfl_xor(r0, 1 << m, 64); r1 += __shfl_xor(r1, 1 << m, 64); }
        o0[p] = r0; o1[p] = r1;
    }
#pragma unroll
    for (int p = 6; p < 10; ++p) {  // qubit p on reg bit (11-p) -> T[9-p]
        float r0 = T0[9 - p], r1 = T1[9 - p];
#pragma unroll
        for (int m = 0; m < 6; ++m) { r0 += __shfl_xor(r0, 1 << m, 64); r1 += __shfl_xor(r1, 1 << m, 64); }
        o0[p] = r0; o1[p] = r1;
    }

    if (lane == 0) {
#pragma unroll
        for (int p = 0; p < NCLASS; ++p) {
            out[s0 * NCLASS + p] = o0[p];
            out[s1 * NCLASS + p] = o1[p];
        }
    }
}

extern "C" void kernel_launch(void* const* d_in, const int* in_sizes, int n_in,
                              void* d_out, int out_size, void* d_ws, size_t ws_size,
                              hipStream_t stream) {
    const float* X = (const float*)d_in[0];
    const float* W = (const float*)d_in[1];
    float* out     = (float*)d_out;
    (void)in_sizes; (void)n_in; (void)out_size; (void)d_ws; (void)ws_size;

    dim3 grid(BATCH / (2 * WPB));   // 2 samples per wave, WPB waves per block
    dim3 block(WPB * 64);
    hipLaunchKernelGGL(vqc_kernel, grid, block, 0, stream, X, W, out);
}